// Round 3
// baseline (202.368 us; speedup 1.0000x reference)
//
#include <hip/hip_runtime.h>
#include <math.h>

#define Bc 2
#define Cc 320
#define Pc 2304
#define HEADSc 8
#define DHc 64
#define INNERc 512
#define Fc 32
#define LN_EPS 1e-5f
#define CHUNKS 18
#define CHUNK_P 128

typedef __attribute__((ext_vector_type(8))) short bf16x8;
typedef __attribute__((ext_vector_type(4))) float f32x4;

static __device__ __forceinline__ ushort f2bf(float x) {
  uint u = __builtin_bit_cast(uint, x);
  u = (u + 0x7fffu + ((u >> 16) & 1u)) >> 16;
  return (ushort)u;
}

// Direct global->LDS DMA, 16B per lane. LDS dest must be wave-uniform base +
// lane*16 (guaranteed by caller: dest = &buf[lin*8] with lin = it*256+tid).
static __device__ __forceinline__ void gload16(const ushort* g, ushort* l) {
  __builtin_amdgcn_global_load_lds(
      (const __attribute__((address_space(1))) uint*)g,
      (__attribute__((address_space(3))) uint*)l, 16, 0, 0);
}

// ---------------------------------------------------------------------------
// Transpose+cast tile helper: src fp32 [R][C] -> dst bf16 [C][R]; 64x64
// ---------------------------------------------------------------------------
static __device__ void transpose_tile(const float* __restrict__ src,
                                      ushort* __restrict__ dst, int R, int C,
                                      int r0, int c0, int tid,
                                      float (*t)[65]) {
#pragma unroll
  for (int it = 0; it < 4; ++it) {
    int lin = it * 256 + tid;
    int rr = lin >> 4, c4 = lin & 15;
    float4 v = *(const float4*)(&src[(size_t)(r0 + rr) * C + c0 + c4 * 4]);
    t[rr][c4 * 4 + 0] = v.x; t[rr][c4 * 4 + 1] = v.y;
    t[rr][c4 * 4 + 2] = v.z; t[rr][c4 * 4 + 3] = v.w;
  }
  __syncthreads();
#pragma unroll
  for (int it = 0; it < 2; ++it) {
    int lin = it * 256 + tid;
    int cc = lin >> 3, r8 = lin & 7;
    ushort tmp[8];
#pragma unroll
    for (int j = 0; j < 8; ++j) tmp[j] = f2bf(t[r8 * 8 + j][cc]);
    *(uint4*)(&dst[(size_t)(c0 + cc) * R + r0 + r8 * 8]) = *(const uint4*)tmp;
  }
}

// ---------------------------------------------------------------------------
// 1. ALL prep in one launch (304 blocks). Also zeroes the chunk counters.
// ---------------------------------------------------------------------------
__global__ __launch_bounds__(256) void prep_all_kernel(
    const float* __restrict__ hs, const float* __restrict__ ehs,
    const float* __restrict__ gamma, const float* __restrict__ beta,
    const float* __restrict__ Wv, const float* __restrict__ Wo,
    const float* __restrict__ exf, const float* __restrict__ Wk,
    const float* __restrict__ dif, const float* __restrict__ Wq,
    ushort* __restrict__ hsT, ushort* __restrict__ ehsT,
    ushort* __restrict__ WvT, ushort* __restrict__ WoT,
    ushort* __restrict__ Gk, ushort* __restrict__ Gq,
    uint* __restrict__ cnt) {
  __shared__ float smem[6448];
  int idx = blockIdx.x, tid = threadIdx.x;
  if (idx == 0 && tid < 16) cnt[tid] = 0;  // for mid_kernel's atomic tail

  if (idx < 144) {
    int pt = idx % 36, z = idx / 36;
    int b = z & 1, which = z >> 1;
    int pos0 = pt * 64;
    const float* src = (which ? ehs : hs) + (size_t)b * Cc * Pc;
    ushort* dst = (which ? ehsT : hsT) + (size_t)b * Pc * Cc;
    float* t = smem;               // [64][65] = 4160
    float* s1 = smem + 4160;       // [4][64]
    float* s2 = smem + 4416;
    float* lmean = smem + 4672;    // [64]
    float* lrstd = smem + 4736;    // [64]
    int lane = tid & 63, g = tid >> 6;
    if (which) {
      const float* base = src + pos0 + lane;
      float sum = 0.f, sq = 0.f;
      for (int c = g * 80; c < g * 80 + 80; ++c) {
        float x = base[(size_t)c * Pc];
        sum += x; sq += x * x;
      }
      s1[g * 64 + lane] = sum; s2[g * 64 + lane] = sq;
      __syncthreads();
      if (tid < 64) {
        float ts = s1[tid] + s1[64 + tid] + s1[128 + tid] + s1[192 + tid];
        float tq = s2[tid] + s2[64 + tid] + s2[128 + tid] + s2[192 + tid];
        float mean = ts / (float)Cc;
        float var = tq / (float)Cc - mean * mean;
        lmean[tid] = mean;
        lrstd[tid] = rsqrtf(var + LN_EPS);
      }
      __syncthreads();
    }
    for (int ct = 0; ct < 5; ++ct) {
      int r0 = ct * 64;
#pragma unroll
      for (int it = 0; it < 4; ++it) {
        int lin = it * 256 + tid;
        int rr = lin >> 4, c4 = lin & 15;
        float4 v = *(const float4*)(&src[(size_t)(r0 + rr) * Pc + pos0 + c4 * 4]);
        t[rr * 65 + c4 * 4 + 0] = v.x; t[rr * 65 + c4 * 4 + 1] = v.y;
        t[rr * 65 + c4 * 4 + 2] = v.z; t[rr * 65 + c4 * 4 + 3] = v.w;
      }
      __syncthreads();
#pragma unroll
      for (int it = 0; it < 2; ++it) {
        int lin = it * 256 + tid;
        int cc = lin >> 3, r8 = lin & 7;
        float m_ = which ? lmean[cc] : 0.f, rs_ = which ? lrstd[cc] : 1.f;
        ushort tmp[8];
#pragma unroll
        for (int j = 0; j < 8; ++j) {
          int ch = r8 * 8 + j;
          float x = t[ch * 65 + cc];
          float val = which ? (x - m_) * rs_ * gamma[r0 + ch] + beta[r0 + ch] : x;
          tmp[j] = f2bf(val);
        }
        *(uint4*)(&dst[(size_t)(pos0 + cc) * Cc + r0 + r8 * 8]) =
            *(const uint4*)tmp;
      }
      __syncthreads();
    }
  } else {
    int idx2 = idx - 144;
    if (idx2 < 40) {
      transpose_tile(Wv, WvT, Cc, INNERc, (idx2 / 8) * 64, (idx2 % 8) * 64,
                     tid, (float(*)[65])smem);
    } else if (idx2 < 80) {
      int i = idx2 - 40;
      transpose_tile(Wo, WoT, INNERc, Cc, (i / 5) * 64, (i % 5) * 64, tid,
                     (float(*)[65])smem);
    } else {
      int i = idx2 - 80;
      int c0 = (i % 5) * 64, h = (i / 5) % 8, zz = i / 40;
      const float* filt = zz ? dif : exf;
      const float* W = zz ? Wq : Wk;
      ushort* G = zz ? Gq : Gk;
      float (*ef)[66] = (float(*)[66])smem;
      float (*wk)[65] = (float(*)[65])(smem + 32 * 66);
      for (int l = tid; l < Fc * DHc; l += 256) {
        int f = l >> 6, d = l & 63;
        ef[f][d] = filt[(size_t)f * INNERc + h * 64 + d];
      }
      for (int l = tid; l < 64 * DHc; l += 256) {
        int cc = l >> 6, d = l & 63;
        wk[cc][d] = W[(size_t)(c0 + cc) * INNERc + h * 64 + d];
      }
      __syncthreads();
      int f = tid >> 3, cbase = tid & 7;
      float acc[8] = {};
#pragma unroll
      for (int d4 = 0; d4 < DHc; d4 += 4) {
        float4 a = *(const float4*)(&ef[f][d4]);
#pragma unroll
        for (int j = 0; j < 8; ++j) {
          float4 b = *(const float4*)(&wk[cbase + j * 8][d4]);
          acc[j] += a.x * b.x + a.y * b.y + a.z * b.z + a.w * b.w;
        }
      }
#pragma unroll
      for (int j = 0; j < 8; ++j)
        G[(size_t)(h * Fc + f) * Cc + c0 + cbase + j * 8] = f2bf(acc[j]);
    }
  }
}

// ---------------------------------------------------------------------------
// 2. MID: spatial attention chunks (even blocks) PARALLEL WITH channel score
//    softmax (odd blocks) in one 576-block launch.
//    Spatial: [V;S] = [WvT_h;Gk_h].ehsT^T, local softmax, O=P.V^T -> svp/mj/lj.
//      Last chunk per (b,h) (device-scope atomic) reduces 18 chunks -> svT.
//    Chan-score: SO = Gq_h.hsT^T, softmax over f, writes Pn[b][h][pos][f] bf16.
// ---------------------------------------------------------------------------
__global__ __launch_bounds__(256) void mid_kernel(
    const ushort* __restrict__ Gk, const ushort* __restrict__ ehsT,
    const ushort* __restrict__ WvT, const ushort* __restrict__ Gq,
    const ushort* __restrict__ hsT, const float* __restrict__ scale_p,
    float* __restrict__ svp, float* __restrict__ mj, float* __restrict__ lj,
    uint* __restrict__ cnt, ushort* __restrict__ svT,
    ushort* __restrict__ Pn) {
  __shared__ alignas(16) char smem[71680];
  __shared__ int lastflag;
  int tid = threadIdx.x;
  int typ = (int)blockIdx.x & 1, sidx = (int)blockIdx.x >> 1;
  int lane = tid & 63, wv = tid >> 6;
  int l15 = lane & 15, kq = lane >> 4;
  float s = scale_p[0];

  if (typ == 0) {
    // ---------------- spatial ----------------
    int c = sidx % CHUNKS, h = (sidx / CHUNKS) & 7, b = sidx / (CHUNKS * 8);
    int pos0 = c * CHUNK_P;
    int bh = b * HEADSc + h;
    ushort* As = (ushort*)smem;            // 96*64
    ushort* Bs = (ushort*)(smem + 12288);  // 128*64
    float* Sq = (float*)(smem + 28672);    // 32*132
    ushort* P = (ushort*)(smem + 45568);   // 32*136
    ushort* Vs = (ushort*)(smem + 54272);  // 64*136

    const ushort* Av = WvT + (size_t)(h * 64) * Cc;
    const ushort* Ag = Gk + (size_t)(h * Fc) * Cc;
    const ushort* Bb = ehsT + ((size_t)b * Pc + pos0) * Cc;

    f32x4 acc[6][2] = {};
    for (int k0 = 0; k0 < Cc; k0 += 64) {
#pragma unroll
      for (int it = 0; it < 3; ++it) {
        int lin = it * 256 + tid;
        int row = lin >> 3, p = lin & 7;
        int lc = p ^ (row & 7);
        const ushort* sp = (row < 64)
                               ? (Av + (size_t)row * Cc + k0 + lc * 8)
                               : (Ag + (size_t)(row - 64) * Cc + k0 + lc * 8);
        gload16(sp, &As[lin * 8]);
      }
#pragma unroll
      for (int it = 0; it < 4; ++it) {
        int lin = it * 256 + tid;
        int row = lin >> 3, p = lin & 7;
        int lc = p ^ (row & 7);
        gload16(Bb + (size_t)row * Cc + k0 + lc * 8, &Bs[lin * 8]);
      }
      __syncthreads();
#pragma unroll
      for (int ss = 0; ss < 2; ++ss) {
        bf16x8 af[6], bfr[2];
#pragma unroll
        for (int mt = 0; mt < 6; ++mt) {
          int m = mt * 16 + l15;
          int p = (ss * 4 + kq) ^ (m & 7);
          af[mt] = *(const bf16x8*)(&As[m * 64 + p * 8]);
        }
#pragma unroll
        for (int nt = 0; nt < 2; ++nt) {
          int n = wv * 32 + nt * 16 + l15;
          int p = (ss * 4 + kq) ^ (n & 7);
          bfr[nt] = *(const bf16x8*)(&Bs[n * 64 + p * 8]);
        }
#pragma unroll
        for (int mt = 0; mt < 6; ++mt)
#pragma unroll
          for (int nt = 0; nt < 2; ++nt)
            acc[mt][nt] = __builtin_amdgcn_mfma_f32_16x16x32_bf16(
                af[mt], bfr[nt], acc[mt][nt], 0, 0, 0);
      }
      __syncthreads();
    }
#pragma unroll
    for (int mt = 0; mt < 6; ++mt)
#pragma unroll
      for (int nt = 0; nt < 2; ++nt) {
        int col = wv * 32 + nt * 16 + l15;
#pragma unroll
        for (int r = 0; r < 4; ++r) {
          int row = mt * 16 + kq * 4 + r;
          if (mt < 4) Vs[row * 136 + col] = f2bf(acc[mt][nt][r]);
          else Sq[(row - 64) * 132 + col] = acc[mt][nt][r];
        }
      }
    __syncthreads();

    {
      int row = tid >> 3, sub = tid & 7;
      float vals[16];
      float m_ = -1e30f;
#pragma unroll
      for (int i = 0; i < 16; ++i) {
        vals[i] = s * Sq[row * 132 + sub * 16 + i];
        m_ = fmaxf(m_, vals[i]);
      }
      m_ = fmaxf(m_, __shfl_xor(m_, 1));
      m_ = fmaxf(m_, __shfl_xor(m_, 2));
      m_ = fmaxf(m_, __shfl_xor(m_, 4));
      float l_ = 0.f;
#pragma unroll
      for (int i = 0; i < 16; i += 2) {
        float e0 = __expf(vals[i] - m_);
        float e1 = __expf(vals[i + 1] - m_);
        l_ += e0 + e1;
        uint pk = (uint)f2bf(e0) | ((uint)f2bf(e1) << 16);
        *(uint*)(&P[row * 136 + sub * 16 + i]) = pk;
      }
      l_ += __shfl_xor(l_, 1);
      l_ += __shfl_xor(l_, 2);
      l_ += __shfl_xor(l_, 4);
      if (sub == 0) {
        mj[((size_t)c * 16 + bh) * Fc + row] = m_;
        lj[((size_t)c * 16 + bh) * Fc + row] = l_;
      }
    }
    __syncthreads();

    f32x4 acc2[2] = {};
#pragma unroll
    for (int ss = 0; ss < 4; ++ss) {
      bf16x8 af[2];
#pragma unroll
      for (int mt = 0; mt < 2; ++mt)
        af[mt] = *(const bf16x8*)(&P[(mt * 16 + l15) * 136 + ss * 32 + kq * 8]);
      bf16x8 bfr = *(const bf16x8*)(&Vs[(wv * 16 + l15) * 136 + ss * 32 + kq * 8]);
#pragma unroll
      for (int mt = 0; mt < 2; ++mt)
        acc2[mt] = __builtin_amdgcn_mfma_f32_16x16x32_bf16(af[mt], bfr,
                                                           acc2[mt], 0, 0, 0);
    }
    float* op = svp + ((size_t)c * 16 + bh) * (Fc * DHc);
#pragma unroll
    for (int mt = 0; mt < 2; ++mt)
#pragma unroll
      for (int r = 0; r < 4; ++r)
        op[(mt * 16 + kq * 4 + r) * DHc + wv * 16 + l15] = acc2[mt][r];

    // ---- atomic last-chunk tail: reduce 18 chunks -> svT[bh] ----
    __threadfence();        // release: make this block's svp/mj/lj visible
    __syncthreads();
    if (tid == 0) {
      uint old = atomicAdd(&cnt[bh], 1u);
      lastflag = (old == CHUNKS - 1) ? 1 : 0;
    }
    __syncthreads();
    if (lastflag) {
      __threadfence();      // acquire: see all other chunks' writes
      int f = tid >> 3, dg = tid & 7;
      float mH = -1e30f;
#pragma unroll
      for (int c2 = 0; c2 < CHUNKS; ++c2)
        mH = fmaxf(mH, mj[((size_t)c2 * 16 + bh) * Fc + f]);
      float lsum = 0.f;
      float osum[8] = {};
#pragma unroll
      for (int c2 = 0; c2 < CHUNKS; ++c2) {
        float w = __expf(mj[((size_t)c2 * 16 + bh) * Fc + f] - mH);
        lsum += w * lj[((size_t)c2 * 16 + bh) * Fc + f];
        const float* sp = svp + ((size_t)c2 * 16 + bh) * (Fc * DHc) + f * DHc +
                          dg * 8;
        float4 a = *(const float4*)sp;
        float4 b2 = *(const float4*)(sp + 4);
        osum[0] += w * a.x; osum[1] += w * a.y;
        osum[2] += w * a.z; osum[3] += w * a.w;
        osum[4] += w * b2.x; osum[5] += w * b2.y;
        osum[6] += w * b2.z; osum[7] += w * b2.w;
      }
      float inv = 1.f / lsum;
#pragma unroll
      for (int j = 0; j < 8; ++j)
        svT[((size_t)bh * DHc + dg * 8 + j) * Fc + f] = f2bf(osum[j] * inv);
    }
  } else {
    // ---------------- channel scores ----------------
    int pb = sidx % 36, hp = (sidx / 36) & 3, b = sidx / 144;
    int pos0 = pb * 64;
    ushort* Aq = (ushort*)smem;            // 2*32*64
    ushort* Bs = (ushort*)(smem + 8192);   // 64*64
    float* SO = (float*)(smem + 16384);    // 64*68
    ushort* Pt = (ushort*)(smem + 33792);  // 64*40
    float* red = (float*)(smem + 38912);   // 4*64

    f32x4 acc[2][2] = {};
    const ushort* Bb = hsT + ((size_t)b * Pc + pos0) * Cc;
    for (int k0 = 0; k0 < Cc; k0 += 64) {
#pragma unroll
      for (int it = 0; it < 2; ++it) {
        int lin = it * 256 + tid;
        int hh = lin >> 8, row = (lin >> 3) & 31, p = lin & 7;
        int lc = p ^ (row & 7);
        gload16(Gq + (size_t)((hp * 2 + hh) * Fc + row) * Cc + k0 + lc * 8,
                &Aq[lin * 8]);
      }
#pragma unroll
      for (int it = 0; it < 2; ++it) {
        int lin = it * 256 + tid;
        int row = lin >> 3, p = lin & 7;
        int lc = p ^ (row & 7);
        gload16(Bb + (size_t)row * Cc + k0 + lc * 8, &Bs[lin * 8]);
      }
      __syncthreads();
#pragma unroll
      for (int ss = 0; ss < 2; ++ss) {
        int n = wv * 16 + l15;
        int pb_ = (ss * 4 + kq) ^ (n & 7);
        bf16x8 bfr = *(const bf16x8*)(&Bs[n * 64 + pb_ * 8]);
#pragma unroll
        for (int hh = 0; hh < 2; ++hh)
#pragma unroll
          for (int mt = 0; mt < 2; ++mt) {
            int m = mt * 16 + l15;
            int pa = (ss * 4 + kq) ^ (m & 7);
            bf16x8 af = *(const bf16x8*)(&Aq[hh * 2048 + m * 64 + pa * 8]);
            acc[hh][mt] = __builtin_amdgcn_mfma_f32_16x16x32_bf16(
                af, bfr, acc[hh][mt], 0, 0, 0);
          }
      }
      __syncthreads();
    }

    for (int hh = 0; hh < 2; ++hh) {
      int h = hp * 2 + hh;
#pragma unroll
      for (int mt = 0; mt < 2; ++mt)
#pragma unroll
        for (int r = 0; r < 4; ++r)
          SO[(mt * 16 + kq * 4 + r) * 68 + wv * 16 + l15] = acc[hh][mt][r];
      __syncthreads();
      {
        int pos = tid & 63, g = tid >> 6;
        float v8[8];
        float pm = -1e30f;
#pragma unroll
        for (int i = 0; i < 8; ++i) {
          v8[i] = s * SO[(g * 8 + i) * 68 + pos];
          pm = fmaxf(pm, v8[i]);
        }
        red[g * 64 + pos] = pm;
        __syncthreads();
        float m_ = fmaxf(fmaxf(red[pos], red[64 + pos]),
                         fmaxf(red[128 + pos], red[192 + pos]));
        __syncthreads();
        float ps = 0.f;
#pragma unroll
        for (int i = 0; i < 8; ++i) {
          v8[i] = __expf(v8[i] - m_);
          ps += v8[i];
        }
        red[g * 64 + pos] = ps;
        __syncthreads();
        float inv = 1.f / (red[pos] + red[64 + pos] + red[128 + pos] +
                           red[192 + pos]);
#pragma unroll
        for (int i = 0; i < 8; i += 2) {
          uint pk =
              (uint)f2bf(v8[i] * inv) | ((uint)f2bf(v8[i + 1] * inv) << 16);
          *(uint*)(&Pt[pos * 40 + g * 8 + i]) = pk;
        }
      }
      __syncthreads();
      {
        int p = tid >> 2, ch = tid & 3;
        *(uint4*)(&Pn[((size_t)(b * HEADSc + h) * Pc + pos0 + p) * Fc +
                      ch * 8]) = *(const uint4*)(&Pt[p * 40 + ch * 8]);
      }
      __syncthreads();
    }
  }
}

// ---------------------------------------------------------------------------
// 3. Fused channel-PV + final GEMM. Per K-tile (= head h):
//    B-tile [128 pos][64 d] = Pn_h(128x32) . svT_h^T(32x64) via MFMA (in LDS),
//    then out-tile accumulate WoT-tile . B-tile. K never leaves LDS.
// ---------------------------------------------------------------------------
__global__ __launch_bounds__(256) void pvgemm_kernel(
    const ushort* __restrict__ WoT, const ushort* __restrict__ Pn,
    const ushort* __restrict__ svT, const float* __restrict__ scale_p,
    const float* __restrict__ bias, const float* __restrict__ res,
    float* __restrict__ Out) {
  int n0 = blockIdx.x * 128, m0 = blockIdx.y * 64, b = blockIdx.z;
  int tid = threadIdx.x, lane = tid & 63, wv = tid >> 6;
  int l15 = lane & 15, kq = lane >> 4;
  __shared__ alignas(16) ushort As[64 * 64];
  __shared__ alignas(16) ushort Ps[128 * 32];
  __shared__ alignas(16) ushort svs[64 * 32];
  __shared__ alignas(16) ushort Bs[128 * 64];
  __shared__ float SOf[128 * 68];

  f32x4 acc[4][2] = {};
  for (int h = 0; h < HEADSc; ++h) {
    const ushort* Ab = WoT + (size_t)m0 * INNERc + h * 64;
    const ushort* Pb = Pn + ((size_t)(b * HEADSc + h) * Pc + n0) * Fc;
    const ushort* Sb = svT + (size_t)(b * HEADSc + h) * DHc * Fc;
#pragma unroll
    for (int it = 0; it < 2; ++it) {
      int lin = it * 256 + tid;
      int row = lin >> 3, p = lin & 7;
      gload16(Ab + (size_t)row * INNERc + ((p ^ (row & 7)) * 8), &As[lin * 8]);
    }
#pragma unroll
    for (int it = 0; it < 2; ++it) {
      int lin = it * 256 + tid;
      int row = lin >> 2, p = lin & 3;
      gload16(Pb + (size_t)row * Fc + ((p ^ (row & 3)) * 8), &Ps[lin * 8]);
    }
    {
      int row = tid >> 2, p = tid & 3;
      gload16(Sb + (size_t)row * Fc + ((p ^ (row & 3)) * 8), &svs[tid * 8]);
    }
    __syncthreads();
    // PV: C[pos 128][d 64], K=32. wave wv owns pos-tiles {wv*2, wv*2+1}.
    f32x4 pv[2][4];
#pragma unroll
    for (int mt = 0; mt < 2; ++mt) {
      int m = (wv * 2 + mt) * 16 + l15;
      bf16x8 af = *(const bf16x8*)(&Ps[m * 32 + (kq ^ (m & 3)) * 8]);
#pragma unroll
      for (int nt = 0; nt < 4; ++nt) {
        int n = nt * 16 + l15;
        bf16x8 bf = *(const bf16x8*)(&svs[n * 32 + (kq ^ (n & 3)) * 8]);
        f32x4 z = {0.f, 0.f, 0.f, 0.f};
        pv[mt][nt] = __builtin_amdgcn_mfma_f32_16x16x32_bf16(af, bf, z, 0, 0, 0);
      }
    }
#pragma unroll
    for (int mt = 0; mt < 2; ++mt)
#pragma unroll
      for (int nt = 0; nt < 4; ++nt)
#pragma unroll
        for (int r = 0; r < 4; ++r)
          SOf[((wv * 2 + mt) * 16 + kq * 4 + r) * 68 + nt * 16 + l15] =
              pv[mt][nt][r];
    __syncthreads();
    // convert SOf -> Bs bf16 (XOR-swizzled rows)
#pragma unroll
    for (int it = 0; it < 4; ++it) {
      int lin = it * 256 + tid;
      int row = lin >> 3, c8 = lin & 7;
      ushort tmp[8];
#pragma unroll
      for (int j = 0; j < 8; ++j) tmp[j] = f2bf(SOf[row * 68 + c8 * 8 + j]);
      *(uint4*)(&Bs[row * 64 + ((c8 ^ (row & 7)) * 8)]) = *(const uint4*)tmp;
    }
    __syncthreads();
    // GEMM accumulate over this head's K=64
#pragma unroll
    for (int ss = 0; ss < 2; ++ss) {
      bf16x8 afr[4], bfr[2];
#pragma unroll
      for (int mt = 0; mt < 4; ++mt) {
        int m = mt * 16 + l15;
        int p = (ss * 4 + kq) ^ (m & 7);
        afr[mt] = *(const bf16x8*)(&As[m * 64 + p * 8]);
      }
#pragma unroll
      for (int nt = 0; nt < 2; ++nt) {
        int n = wv * 32 + nt * 16 + l15;
        int p = (ss * 4 + kq) ^ (n & 7);
        bfr[nt] = *(const bf16x8*)(&Bs[n * 64 + p * 8]);
      }
#pragma unroll
      for (int mt = 0; mt < 4; ++mt)
#pragma unroll
        for (int nt = 0; nt < 2; ++nt)
          acc[mt][nt] = __builtin_amdgcn_mfma_f32_16x16x32_bf16(
              afr[mt], bfr[nt], acc[mt][nt], 0, 0, 0);
    }
    __syncthreads();
  }
  float s = scale_p[0];
  float* Ob = Out + ((size_t)b * Cc + m0) * Pc + n0;
  const float* rb = res + ((size_t)b * Cc + m0) * Pc + n0;
#pragma unroll
  for (int mt = 0; mt < 4; ++mt)
#pragma unroll
    for (int nt = 0; nt < 2; ++nt) {
      int ncol = wv * 32 + nt * 16 + l15;
#pragma unroll
      for (int r = 0; r < 4; ++r) {
        int m = mt * 16 + kq * 4 + r;
        Ob[(size_t)m * Pc + ncol] =
            acc[mt][nt][r] + bias[m0 + m] + s * rb[(size_t)m * Pc + ncol];
      }
    }
}

// ---------------------------------------------------------------------------
extern "C" void kernel_launch(void* const* d_in, const int* in_sizes, int n_in,
                              void* d_out, int out_size, void* d_ws, size_t ws_size,
                              hipStream_t stream) {
  const float* hs    = (const float*)d_in[0];
  const float* ehs   = (const float*)d_in[1];
  const float* Wq    = (const float*)d_in[2];
  const float* Wk    = (const float*)d_in[3];
  const float* Wv    = (const float*)d_in[4];
  const float* Wo    = (const float*)d_in[5];
  const float* bo    = (const float*)d_in[6];
  const float* gamma = (const float*)d_in[7];
  const float* beta  = (const float*)d_in[8];
  const float* exf   = (const float*)d_in[9];
  const float* dif   = (const float*)d_in[10];
  const float* scale = (const float*)d_in[11];
  float* out = (float*)d_out;

  float* ws = (float*)d_ws;
  float* svp = ws;                         //   589,824 f
  float* mj  = svp + 589824;               //     9,216 f
  float* lj  = mj + 9216;                  //     9,216 f
  uint*  cnt = (uint*)(lj + 9216);         //        16 u32
  ushort* hsT  = (ushort*)(cnt + 16);      // 1,474,560 us
  ushort* ehsT = hsT + 1474560;            // 1,474,560 us
  ushort* WvT  = ehsT + 1474560;           //   163,840 us
  ushort* WoT  = WvT + 163840;             //   163,840 us
  ushort* Gk   = WoT + 163840;             //    81,920 us
  ushort* Gq   = Gk + 81920;               //    81,920 us
  ushort* svT  = Gq + 81920;               //    32,768 us
  ushort* Pn   = svT + 32768;              // 1,179,648 us

  prep_all_kernel<<<dim3(304), dim3(256), 0, stream>>>(
      hs, ehs, gamma, beta, Wv, Wo, exf, Wk, dif, Wq,
      hsT, ehsT, WvT, WoT, Gk, Gq, cnt);
  mid_kernel<<<dim3(576), dim3(256), 0, stream>>>(
      Gk, ehsT, WvT, Gq, hsT, scale, svp, mj, lj, cnt, svT, Pn);
  pvgemm_kernel<<<dim3(Pc / 128, Cc / 64, Bc), dim3(256), 0, stream>>>(
      WoT, Pn, svT, scale, bo, hs, out);
}

// Round 4
// 133.208 us; speedup vs baseline: 1.5192x; 1.5192x over previous
//
#include <hip/hip_runtime.h>
#include <math.h>

#define Bc 2
#define Cc 320
#define Pc 2304
#define HEADSc 8
#define DHc 64
#define INNERc 512
#define Fc 32
#define LN_EPS 1e-5f
#define CHUNKS 36
#define CHUNK_P 64

typedef __attribute__((ext_vector_type(8))) short bf16x8;
typedef __attribute__((ext_vector_type(4))) float f32x4;

static __device__ __forceinline__ ushort f2bf(float x) {
  uint u = __builtin_bit_cast(uint, x);
  u = (u + 0x7fffu + ((u >> 16) & 1u)) >> 16;
  return (ushort)u;
}

// Direct global->LDS DMA, 16B per lane. LDS dest must be wave-uniform base +
// lane*16 (guaranteed by caller: dest = &buf[lin*8] with lin = it*256+tid).
static __device__ __forceinline__ void gload16(const ushort* g, ushort* l) {
  __builtin_amdgcn_global_load_lds(
      (const __attribute__((address_space(1))) uint*)g,
      (__attribute__((address_space(3))) uint*)l, 16, 0, 0);
}

// ---------------------------------------------------------------------------
// Transpose+cast tile helper: src fp32 [R][C] -> dst bf16 [C][R]; 64x64
// ---------------------------------------------------------------------------
static __device__ void transpose_tile(const float* __restrict__ src,
                                      ushort* __restrict__ dst, int R, int C,
                                      int r0, int c0, int tid,
                                      float (*t)[65]) {
#pragma unroll
  for (int it = 0; it < 4; ++it) {
    int lin = it * 256 + tid;
    int rr = lin >> 4, c4 = lin & 15;
    float4 v = *(const float4*)(&src[(size_t)(r0 + rr) * C + c0 + c4 * 4]);
    t[rr][c4 * 4 + 0] = v.x; t[rr][c4 * 4 + 1] = v.y;
    t[rr][c4 * 4 + 2] = v.z; t[rr][c4 * 4 + 3] = v.w;
  }
  __syncthreads();
#pragma unroll
  for (int it = 0; it < 2; ++it) {
    int lin = it * 256 + tid;
    int cc = lin >> 3, r8 = lin & 7;
    ushort tmp[8];
#pragma unroll
    for (int j = 0; j < 8; ++j) tmp[j] = f2bf(t[r8 * 8 + j][cc]);
    *(uint4*)(&dst[(size_t)(c0 + cc) * R + r0 + r8 * 8]) = *(const uint4*)tmp;
  }
}

// ---------------------------------------------------------------------------
// 1. ALL prep in one launch (304 blocks).
// ---------------------------------------------------------------------------
__global__ __launch_bounds__(256) void prep_all_kernel(
    const float* __restrict__ hs, const float* __restrict__ ehs,
    const float* __restrict__ gamma, const float* __restrict__ beta,
    const float* __restrict__ Wv, const float* __restrict__ Wo,
    const float* __restrict__ exf, const float* __restrict__ Wk,
    const float* __restrict__ dif, const float* __restrict__ Wq,
    ushort* __restrict__ hsT, ushort* __restrict__ ehsT,
    ushort* __restrict__ WvT, ushort* __restrict__ WoT,
    ushort* __restrict__ Gk, ushort* __restrict__ Gq) {
  __shared__ float smem[6448];
  int idx = blockIdx.x, tid = threadIdx.x;

  if (idx < 144) {
    int pt = idx % 36, z = idx / 36;
    int b = z & 1, which = z >> 1;
    int pos0 = pt * 64;
    const float* src = (which ? ehs : hs) + (size_t)b * Cc * Pc;
    ushort* dst = (which ? ehsT : hsT) + (size_t)b * Pc * Cc;
    float* t = smem;               // [64][65] = 4160
    float* s1 = smem + 4160;       // [4][64]
    float* s2 = smem + 4416;
    float* lmean = smem + 4672;    // [64]
    float* lrstd = smem + 4736;    // [64]
    int lane = tid & 63, g = tid >> 6;
    if (which) {
      const float* base = src + pos0 + lane;
      float sum = 0.f, sq = 0.f;
      for (int c = g * 80; c < g * 80 + 80; ++c) {
        float x = base[(size_t)c * Pc];
        sum += x; sq += x * x;
      }
      s1[g * 64 + lane] = sum; s2[g * 64 + lane] = sq;
      __syncthreads();
      if (tid < 64) {
        float ts = s1[tid] + s1[64 + tid] + s1[128 + tid] + s1[192 + tid];
        float tq = s2[tid] + s2[64 + tid] + s2[128 + tid] + s2[192 + tid];
        float mean = ts / (float)Cc;
        float var = tq / (float)Cc - mean * mean;
        lmean[tid] = mean;
        lrstd[tid] = rsqrtf(var + LN_EPS);
      }
      __syncthreads();
    }
    for (int ct = 0; ct < 5; ++ct) {
      int r0 = ct * 64;
#pragma unroll
      for (int it = 0; it < 4; ++it) {
        int lin = it * 256 + tid;
        int rr = lin >> 4, c4 = lin & 15;
        float4 v = *(const float4*)(&src[(size_t)(r0 + rr) * Pc + pos0 + c4 * 4]);
        t[rr * 65 + c4 * 4 + 0] = v.x; t[rr * 65 + c4 * 4 + 1] = v.y;
        t[rr * 65 + c4 * 4 + 2] = v.z; t[rr * 65 + c4 * 4 + 3] = v.w;
      }
      __syncthreads();
#pragma unroll
      for (int it = 0; it < 2; ++it) {
        int lin = it * 256 + tid;
        int cc = lin >> 3, r8 = lin & 7;
        float m_ = which ? lmean[cc] : 0.f, rs_ = which ? lrstd[cc] : 1.f;
        ushort tmp[8];
#pragma unroll
        for (int j = 0; j < 8; ++j) {
          int ch = r8 * 8 + j;
          float x = t[ch * 65 + cc];
          float val = which ? (x - m_) * rs_ * gamma[r0 + ch] + beta[r0 + ch] : x;
          tmp[j] = f2bf(val);
        }
        *(uint4*)(&dst[(size_t)(pos0 + cc) * Cc + r0 + r8 * 8]) =
            *(const uint4*)tmp;
      }
      __syncthreads();
    }
  } else {
    int idx2 = idx - 144;
    if (idx2 < 40) {
      transpose_tile(Wv, WvT, Cc, INNERc, (idx2 / 8) * 64, (idx2 % 8) * 64,
                     tid, (float(*)[65])smem);
    } else if (idx2 < 80) {
      int i = idx2 - 40;
      transpose_tile(Wo, WoT, INNERc, Cc, (i / 5) * 64, (i % 5) * 64, tid,
                     (float(*)[65])smem);
    } else {
      int i = idx2 - 80;
      int c0 = (i % 5) * 64, h = (i / 5) % 8, zz = i / 40;
      const float* filt = zz ? dif : exf;
      const float* W = zz ? Wq : Wk;
      ushort* G = zz ? Gq : Gk;
      float (*ef)[66] = (float(*)[66])smem;
      float (*wk)[65] = (float(*)[65])(smem + 32 * 66);
      for (int l = tid; l < Fc * DHc; l += 256) {
        int f = l >> 6, d = l & 63;
        ef[f][d] = filt[(size_t)f * INNERc + h * 64 + d];
      }
      for (int l = tid; l < 64 * DHc; l += 256) {
        int cc = l >> 6, d = l & 63;
        wk[cc][d] = W[(size_t)(c0 + cc) * INNERc + h * 64 + d];
      }
      __syncthreads();
      int f = tid >> 3, cbase = tid & 7;
      float acc[8] = {};
#pragma unroll
      for (int d4 = 0; d4 < DHc; d4 += 4) {
        float4 a = *(const float4*)(&ef[f][d4]);
#pragma unroll
        for (int j = 0; j < 8; ++j) {
          float4 b = *(const float4*)(&wk[cbase + j * 8][d4]);
          acc[j] += a.x * b.x + a.y * b.y + a.z * b.z + a.w * b.w;
        }
      }
#pragma unroll
      for (int j = 0; j < 8; ++j)
        G[(size_t)(h * Fc + f) * Cc + c0 + cbase + j * 8] = f2bf(acc[j]);
    }
  }
}

// ---------------------------------------------------------------------------
// 2. Spatial attention, CHUNK_P=64 -> 576 blocks. LDS phase-union = 22.5 KiB
//    (was 70.5): phase1 {As[96][64], Bs[64][64]}, phase2 {Sq, Vs, P} overlaid.
// ---------------------------------------------------------------------------
__global__ __launch_bounds__(256) void spatial_kernel(
    const ushort* __restrict__ Gk, const ushort* __restrict__ ehsT,
    const ushort* __restrict__ WvT, const float* __restrict__ scale_p,
    float* __restrict__ svp, float* __restrict__ mj, float* __restrict__ lj) {
  int c = blockIdx.x, h = blockIdx.y, b = blockIdx.z;
  int tid = threadIdx.x, lane = tid & 63, wv = tid >> 6;
  int l15 = lane & 15, kq = lane >> 4;
  int pos0 = c * CHUNK_P;
  int bh = b * HEADSc + h;
  float s = scale_p[0];

  // union: phase1 As@0 (12288), Bs@12288 (8192) | phase2 Sq@0 (8704 fp32),
  // Vs@8704 (9216), P@17920 (4608). total 22528 B.
  __shared__ alignas(16) char smem[22528];
  ushort* As = (ushort*)smem;
  ushort* Bs = (ushort*)(smem + 12288);
  float* Sq = (float*)smem;              // [32][68]
  ushort* Vs = (ushort*)(smem + 8704);   // [64][72]
  ushort* P = (ushort*)(smem + 17920);   // [32][72]

  const ushort* Av = WvT + (size_t)(h * 64) * Cc;
  const ushort* Ag = Gk + (size_t)(h * Fc) * Cc;
  const ushort* Bb = ehsT + ((size_t)b * Pc + pos0) * Cc;

  f32x4 acc[6] = {};
  for (int k0 = 0; k0 < Cc; k0 += 64) {
#pragma unroll
    for (int it = 0; it < 3; ++it) {
      int lin = it * 256 + tid;       // 768: 96 rows x 8
      int row = lin >> 3, p = lin & 7;
      int lc = p ^ (row & 7);
      const ushort* sp = (row < 64) ? (Av + (size_t)row * Cc + k0 + lc * 8)
                                    : (Ag + (size_t)(row - 64) * Cc + k0 + lc * 8);
      gload16(sp, &As[lin * 8]);
    }
#pragma unroll
    for (int it = 0; it < 2; ++it) {
      int lin = it * 256 + tid;       // 512: 64 rows x 8
      int row = lin >> 3, p = lin & 7;
      int lc = p ^ (row & 7);
      gload16(Bb + (size_t)row * Cc + k0 + lc * 8, &Bs[lin * 8]);
    }
    __syncthreads();
#pragma unroll
    for (int ss = 0; ss < 2; ++ss) {
      bf16x8 af[6], bfr;
#pragma unroll
      for (int mt = 0; mt < 6; ++mt) {
        int m = mt * 16 + l15;
        int p = (ss * 4 + kq) ^ (m & 7);
        af[mt] = *(const bf16x8*)(&As[m * 64 + p * 8]);
      }
      {
        int n = wv * 16 + l15;
        int p = (ss * 4 + kq) ^ (n & 7);
        bfr = *(const bf16x8*)(&Bs[n * 64 + p * 8]);
      }
#pragma unroll
      for (int mt = 0; mt < 6; ++mt)
        acc[mt] = __builtin_amdgcn_mfma_f32_16x16x32_bf16(af[mt], bfr, acc[mt],
                                                          0, 0, 0);
    }
    __syncthreads();
  }
  // scatter: mt<4 -> Vs (bf16) [d][pos], mt 4..5 -> Sq (fp32) [f][pos]
#pragma unroll
  for (int mt = 0; mt < 6; ++mt) {
    int col = wv * 16 + l15;
#pragma unroll
    for (int r = 0; r < 4; ++r) {
      int row = mt * 16 + kq * 4 + r;
      if (mt < 4) Vs[row * 72 + col] = f2bf(acc[mt][r]);
      else Sq[(row - 64) * 68 + col] = acc[mt][r];
    }
  }
  __syncthreads();

  // per-row (f) local max + exp-sum over 64 cols; P = exp(s*S - m)
  {
    int row = tid >> 3, sub = tid & 7;
    float vals[8];
    float m_ = -1e30f;
#pragma unroll
    for (int i = 0; i < 8; ++i) {
      vals[i] = s * Sq[row * 68 + sub * 8 + i];
      m_ = fmaxf(m_, vals[i]);
    }
    m_ = fmaxf(m_, __shfl_xor(m_, 1));
    m_ = fmaxf(m_, __shfl_xor(m_, 2));
    m_ = fmaxf(m_, __shfl_xor(m_, 4));
    float l_ = 0.f;
#pragma unroll
    for (int i = 0; i < 8; i += 2) {
      float e0 = __expf(vals[i] - m_);
      float e1 = __expf(vals[i + 1] - m_);
      l_ += e0 + e1;
      uint pk = (uint)f2bf(e0) | ((uint)f2bf(e1) << 16);
      *(uint*)(&P[row * 72 + sub * 8 + i]) = pk;
    }
    l_ += __shfl_xor(l_, 1);
    l_ += __shfl_xor(l_, 2);
    l_ += __shfl_xor(l_, 4);
    if (sub == 0) {
      mj[((size_t)c * 16 + bh) * Fc + row] = m_;
      lj[((size_t)c * 16 + bh) * Fc + row] = l_;
    }
  }
  __syncthreads();

  // O = P(32x64) . V^T  (M=32, N=64, K=64)
  f32x4 acc2[2] = {};
#pragma unroll
  for (int ss = 0; ss < 2; ++ss) {
    bf16x8 af[2];
#pragma unroll
    for (int mt = 0; mt < 2; ++mt)
      af[mt] = *(const bf16x8*)(&P[(mt * 16 + l15) * 72 + ss * 32 + kq * 8]);
    bf16x8 bfr = *(const bf16x8*)(&Vs[(wv * 16 + l15) * 72 + ss * 32 + kq * 8]);
#pragma unroll
    for (int mt = 0; mt < 2; ++mt)
      acc2[mt] = __builtin_amdgcn_mfma_f32_16x16x32_bf16(af[mt], bfr, acc2[mt],
                                                         0, 0, 0);
  }
  float* op = svp + ((size_t)c * 16 + bh) * (Fc * DHc);
#pragma unroll
  for (int mt = 0; mt < 2; ++mt)
#pragma unroll
    for (int r = 0; r < 4; ++r)
      op[(mt * 16 + kq * 4 + r) * DHc + wv * 16 + l15] = acc2[mt][r];
}

// ---------------------------------------------------------------------------
// 3. Online-softmax reduce of 36 chunks -> svT[bh][d][f] bf16
// ---------------------------------------------------------------------------
__global__ __launch_bounds__(256) void sv_reduce_kernel(
    const float* __restrict__ svp, const float* __restrict__ mj,
    const float* __restrict__ lj, ushort* __restrict__ svT) {
  int idx = blockIdx.x * 256 + threadIdx.x;  // 32768
  int d = idx & 63, fr = idx >> 6;
  int bh = fr >> 5, f = fr & 31;
  float m = -1e30f;
#pragma unroll
  for (int c = 0; c < CHUNKS; ++c)
    m = fmaxf(m, mj[((size_t)c * 16 + bh) * Fc + f]);
  float osum = 0.f, lsum = 0.f;
#pragma unroll 4
  for (int c = 0; c < CHUNKS; ++c) {
    float w = __expf(mj[((size_t)c * 16 + bh) * Fc + f] - m);
    osum += w * svp[((size_t)c * 16 + bh) * (Fc * DHc) + f * DHc + d];
    lsum += w * lj[((size_t)c * 16 + bh) * Fc + f];
  }
  svT[((size_t)bh * DHc + d) * Fc + f] = f2bf(osum / lsum);
}

// ---------------------------------------------------------------------------
// 4. Channel attention, one head per block -> 576 blocks. LDS union = 28 KiB
//    (was 44): phase1 {Aq[32][64], Bs[64][64]}, phase2 {SO, Pt, svs, red}.
// ---------------------------------------------------------------------------
__global__ __launch_bounds__(256) void channel_kernel(
    const ushort* __restrict__ Gq, const ushort* __restrict__ hsT,
    const ushort* __restrict__ svT, const float* __restrict__ scale_p,
    ushort* __restrict__ OAT) {
  int pb = blockIdx.x, h = blockIdx.y, b = blockIdx.z;
  int pos0 = pb * 64;
  int tid = threadIdx.x, lane = tid & 63, wv = tid >> 6;
  int l15 = lane & 15, kq = lane >> 4;
  float s = scale_p[0];

  // union: phase1 Aq@0 (4096), Bs@4096 (8192) | phase2 SO@0 (64*68*4=17408),
  // Pt@17408 (5120), svs@22528 (5120), red@27648 (1024). total 28672 B.
  __shared__ alignas(16) char smem[28672];
  ushort* Aq = (ushort*)smem;
  ushort* Bs = (ushort*)(smem + 4096);
  float* SO = (float*)smem;               // [64][68] (scores use rows 0-31)
  ushort* Pt = (ushort*)(smem + 17408);   // [64][40]
  ushort* svs = (ushort*)(smem + 22528);  // [64][40]
  float* red = (float*)(smem + 27648);    // [4][64]

  f32x4 acc[2] = {};
  const ushort* Bb = hsT + ((size_t)b * Pc + pos0) * Cc;
  const ushort* Ab = Gq + (size_t)(h * Fc) * Cc;
  for (int k0 = 0; k0 < Cc; k0 += 64) {
    {
      int lin = tid;                  // 256: 32 rows x 8
      int row = lin >> 3, p = lin & 7;
      int lc = p ^ (row & 7);
      gload16(Ab + (size_t)row * Cc + k0 + lc * 8, &Aq[lin * 8]);
    }
#pragma unroll
    for (int it = 0; it < 2; ++it) {
      int lin = it * 256 + tid;       // 512: 64 rows x 8
      int row = lin >> 3, p = lin & 7;
      int lc = p ^ (row & 7);
      gload16(Bb + (size_t)row * Cc + k0 + lc * 8, &Bs[lin * 8]);
    }
    __syncthreads();
#pragma unroll
    for (int ss = 0; ss < 2; ++ss) {
      int n = wv * 16 + l15;
      int pb_ = (ss * 4 + kq) ^ (n & 7);
      bf16x8 bfr = *(const bf16x8*)(&Bs[n * 64 + pb_ * 8]);
#pragma unroll
      for (int mt = 0; mt < 2; ++mt) {
        int m = mt * 16 + l15;
        int pa = (ss * 4 + kq) ^ (m & 7);
        bf16x8 af = *(const bf16x8*)(&Aq[m * 64 + pa * 8]);
        acc[mt] = __builtin_amdgcn_mfma_f32_16x16x32_bf16(af, bfr, acc[mt],
                                                          0, 0, 0);
      }
    }
    __syncthreads();
  }

  // scatter scores -> SO rows 0..31 (f), cols 0..63 (pos); load svs
#pragma unroll
  for (int mt = 0; mt < 2; ++mt)
#pragma unroll
    for (int r = 0; r < 4; ++r)
      SO[(mt * 16 + kq * 4 + r) * 68 + wv * 16 + l15] = acc[mt][r];
  {
    int rr = tid >> 2, p = tid & 3;
    *(uint4*)(&svs[rr * 40 + p * 8]) = *(const uint4*)(
        svT + ((size_t)(b * HEADSc + h) * DHc + rr) * Fc + p * 8);
  }
  __syncthreads();
  // softmax over f (32) per pos (64)
  {
    int pos = tid & 63, g = tid >> 6;
    float v8[8];
    float pm = -1e30f;
#pragma unroll
    for (int i = 0; i < 8; ++i) {
      v8[i] = s * SO[(g * 8 + i) * 68 + pos];
      pm = fmaxf(pm, v8[i]);
    }
    red[g * 64 + pos] = pm;
    __syncthreads();
    float m_ = fmaxf(fmaxf(red[pos], red[64 + pos]),
                     fmaxf(red[128 + pos], red[192 + pos]));
    __syncthreads();
    float ps = 0.f;
#pragma unroll
    for (int i = 0; i < 8; ++i) {
      v8[i] = __expf(v8[i] - m_);
      ps += v8[i];
    }
    red[g * 64 + pos] = ps;
    __syncthreads();
    float inv = 1.f / (red[pos] + red[64 + pos] + red[128 + pos] +
                       red[192 + pos]);
#pragma unroll
    for (int i = 0; i < 8; i += 2) {
      uint pk = (uint)f2bf(v8[i] * inv) | ((uint)f2bf(v8[i + 1] * inv) << 16);
      *(uint*)(&Pt[pos * 40 + g * 8 + i]) = pk;
    }
  }
  __syncthreads();
  // PV: out[pos 64][d 64] = Pt(64x32) . svs^T ; write into SO rows 0..63
  {
    bf16x8 b_ = *(const bf16x8*)(&svs[(wv * 16 + l15) * 40 + kq * 8]);
    f32x4 acc3[4];
#pragma unroll
    for (int mt = 0; mt < 4; ++mt) {
      bf16x8 a_ = *(const bf16x8*)(&Pt[(mt * 16 + l15) * 40 + kq * 8]);
      f32x4 z = {0.f, 0.f, 0.f, 0.f};
      acc3[mt] = __builtin_amdgcn_mfma_f32_16x16x32_bf16(a_, b_, z, 0, 0, 0);
    }
#pragma unroll
    for (int mt = 0; mt < 4; ++mt)
#pragma unroll
      for (int r = 0; r < 4; ++r)
        SO[(mt * 16 + kq * 4 + r) * 68 + wv * 16 + l15] = acc3[mt][r];
  }
  __syncthreads();
#pragma unroll
  for (int it = 0; it < 2; ++it) {
    int lin = it * 256 + tid;
    int p = lin >> 3, c8 = lin & 7;
    ushort tmp[8];
#pragma unroll
    for (int j = 0; j < 8; ++j) tmp[j] = f2bf(SO[p * 68 + c8 * 8 + j]);
    *(uint4*)(&OAT[((size_t)b * Pc + pos0 + p) * INNERc + h * 64 + c8 * 8]) =
        *(const uint4*)tmp;
  }
}

// ---------------------------------------------------------------------------
// 5. Final GEMM: out = WoT . OAT + bias + s*res. K=512. 64x64 tiles -> 360
//    blocks (was 180 at 64x128, which left 76 CUs idle).
// ---------------------------------------------------------------------------
__global__ __launch_bounds__(256) void gemm_mfma_kernel(
    const ushort* __restrict__ A, const ushort* __restrict__ Bt,
    float* __restrict__ Out, int K, int Mdim,
    const float* __restrict__ bias, const float* __restrict__ res,
    const float* __restrict__ scale_p) {
  int b = blockIdx.z;
  int n0 = blockIdx.x * 64, m0 = blockIdx.y * 64;
  int tid = threadIdx.x, lane = tid & 63, wv = tid >> 6;
  int l15 = lane & 15, kq = lane >> 4;
  __shared__ alignas(16) ushort As[64 * 64];
  __shared__ alignas(16) ushort Bs[64 * 64];
  const ushort* Ab = A + (size_t)m0 * K;
  const ushort* Bb = Bt + ((size_t)b * Pc + n0) * K;

  f32x4 acc[4] = {};
  for (int k0 = 0; k0 < K; k0 += 64) {
#pragma unroll
    for (int it = 0; it < 2; ++it) {
      int lin = it * 256 + tid;
      int row = lin >> 3, p = lin & 7;
      int lc = p ^ (row & 7);
      gload16(Ab + (size_t)row * K + k0 + lc * 8, &As[lin * 8]);
    }
#pragma unroll
    for (int it = 0; it < 2; ++it) {
      int lin = it * 256 + tid;
      int row = lin >> 3, p = lin & 7;
      int lc = p ^ (row & 7);
      gload16(Bb + (size_t)row * K + k0 + lc * 8, &Bs[lin * 8]);
    }
    __syncthreads();
#pragma unroll
    for (int ss = 0; ss < 2; ++ss) {
      bf16x8 af[4], bfr;
#pragma unroll
      for (int mt = 0; mt < 4; ++mt) {
        int m = mt * 16 + l15;
        int p = (ss * 4 + kq) ^ (m & 7);
        af[mt] = *(const bf16x8*)(&As[m * 64 + p * 8]);
      }
      {
        int n = wv * 16 + l15;
        int p = (ss * 4 + kq) ^ (n & 7);
        bfr = *(const bf16x8*)(&Bs[n * 64 + p * 8]);
      }
#pragma unroll
      for (int mt = 0; mt < 4; ++mt)
        acc[mt] = __builtin_amdgcn_mfma_f32_16x16x32_bf16(af[mt], bfr, acc[mt],
                                                          0, 0, 0);
    }
    __syncthreads();
  }
  float s = scale_p[0];
  float* Ob = Out + ((size_t)b * Mdim + m0) * Pc + n0;
  const float* rb = res + ((size_t)b * Mdim + m0) * Pc + n0;
  int ncol = wv * 16 + l15;
#pragma unroll
  for (int mt = 0; mt < 4; ++mt)
#pragma unroll
    for (int r = 0; r < 4; ++r) {
      int m = mt * 16 + kq * 4 + r;
      Ob[(size_t)m * Pc + ncol] =
          acc[mt][r] + bias[m0 + m] + s * rb[(size_t)m * Pc + ncol];
    }
}

// ---------------------------------------------------------------------------
extern "C" void kernel_launch(void* const* d_in, const int* in_sizes, int n_in,
                              void* d_out, int out_size, void* d_ws, size_t ws_size,
                              hipStream_t stream) {
  const float* hs    = (const float*)d_in[0];
  const float* ehs   = (const float*)d_in[1];
  const float* Wq    = (const float*)d_in[2];
  const float* Wk    = (const float*)d_in[3];
  const float* Wv    = (const float*)d_in[4];
  const float* Wo    = (const float*)d_in[5];
  const float* bo    = (const float*)d_in[6];
  const float* gamma = (const float*)d_in[7];
  const float* beta  = (const float*)d_in[8];
  const float* exf   = (const float*)d_in[9];
  const float* dif   = (const float*)d_in[10];
  const float* scale = (const float*)d_in[11];
  float* out = (float*)d_out;

  float* ws = (float*)d_ws;
  float* svp = ws;                         // 36*16*2048 = 1,179,648 f
  float* mj  = svp + 1179648;              //    18,432 f
  float* lj  = mj + 18432;                 //    18,432 f
  ushort* hsT  = (ushort*)(lj + 18432);    // 1,474,560 us
  ushort* ehsT = hsT + 1474560;            // 1,474,560 us
  ushort* WvT  = ehsT + 1474560;           //   163,840 us
  ushort* WoT  = WvT + 163840;             //   163,840 us
  ushort* Gk   = WoT + 163840;             //    81,920 us
  ushort* Gq   = Gk + 81920;               //    81,920 us
  ushort* svT  = Gq + 81920;               //    32,768 us
  ushort* OAT  = svT + 32768;              // 2,359,296 us

  prep_all_kernel<<<dim3(304), dim3(256), 0, stream>>>(
      hs, ehs, gamma, beta, Wv, Wo, exf, Wk, dif, Wq,
      hsT, ehsT, WvT, WoT, Gk, Gq);
  spatial_kernel<<<dim3(CHUNKS, HEADSc, Bc), dim3(256), 0, stream>>>(
      Gk, ehsT, WvT, scale, svp, mj, lj);
  sv_reduce_kernel<<<dim3(128), dim3(256), 0, stream>>>(svp, mj, lj, svT);
  channel_kernel<<<dim3(Pc / 64, HEADSc, Bc), dim3(256), 0, stream>>>(
      Gq, hsT, svT, scale, OAT);
  gemm_mfma_kernel<<<dim3(Pc / 64, Cc / 64, Bc), dim3(256), 0, stream>>>(
      WoT, OAT, out, INNERc, Cc, bo, hs, scale);
}

// Round 5
// 131.302 us; speedup vs baseline: 1.5412x; 1.0145x over previous
//
#include <hip/hip_runtime.h>
#include <math.h>

#define Bc 2
#define Cc 320
#define Pc 2304
#define HEADSc 8
#define DHc 64
#define INNERc 512
#define Fc 32
#define LN_EPS 1e-5f
#define CHUNKS 36
#define CHUNK_P 64

typedef __attribute__((ext_vector_type(8))) short bf16x8;
typedef __attribute__((ext_vector_type(4))) float f32x4;

static __device__ __forceinline__ ushort f2bf(float x) {
  uint u = __builtin_bit_cast(uint, x);
  u = (u + 0x7fffu + ((u >> 16) & 1u)) >> 16;
  return (ushort)u;
}

// Direct global->LDS DMA, 16B per lane. LDS dest must be wave-uniform base +
// lane*16 (guaranteed by caller: dest = &buf[lin*8] with lin = it*256+tid).
static __device__ __forceinline__ void gload16(const ushort* g, ushort* l) {
  __builtin_amdgcn_global_load_lds(
      (const __attribute__((address_space(1))) uint*)g,
      (__attribute__((address_space(3))) uint*)l, 16, 0, 0);
}

// ---------------------------------------------------------------------------
// Transpose+cast tile helper: src fp32 [R][C] -> dst bf16 [C][R]; 64x64
// ---------------------------------------------------------------------------
static __device__ void transpose_tile(const float* __restrict__ src,
                                      ushort* __restrict__ dst, int R, int C,
                                      int r0, int c0, int tid,
                                      float (*t)[65]) {
#pragma unroll
  for (int it = 0; it < 4; ++it) {
    int lin = it * 256 + tid;
    int rr = lin >> 4, c4 = lin & 15;
    float4 v = *(const float4*)(&src[(size_t)(r0 + rr) * C + c0 + c4 * 4]);
    t[rr][c4 * 4 + 0] = v.x; t[rr][c4 * 4 + 1] = v.y;
    t[rr][c4 * 4 + 2] = v.z; t[rr][c4 * 4 + 3] = v.w;
  }
  __syncthreads();
#pragma unroll
  for (int it = 0; it < 2; ++it) {
    int lin = it * 256 + tid;
    int cc = lin >> 3, r8 = lin & 7;
    ushort tmp[8];
#pragma unroll
    for (int j = 0; j < 8; ++j) tmp[j] = f2bf(t[r8 * 8 + j][cc]);
    *(uint4*)(&dst[(size_t)(c0 + cc) * R + r0 + r8 * 8]) = *(const uint4*)tmp;
  }
}

// ---------------------------------------------------------------------------
// 1. ALL prep in one launch (304 blocks). Activation path register-prefetches
//    the next 64x64 tile while transposing the current one.
// ---------------------------------------------------------------------------
__global__ __launch_bounds__(256) void prep_all_kernel(
    const float* __restrict__ hs, const float* __restrict__ ehs,
    const float* __restrict__ gamma, const float* __restrict__ beta,
    const float* __restrict__ Wv, const float* __restrict__ Wo,
    const float* __restrict__ exf, const float* __restrict__ Wk,
    const float* __restrict__ dif, const float* __restrict__ Wq,
    ushort* __restrict__ hsT, ushort* __restrict__ ehsT,
    ushort* __restrict__ WvT, ushort* __restrict__ WoT,
    ushort* __restrict__ Gk, ushort* __restrict__ Gq) {
  __shared__ float smem[6448];
  int idx = blockIdx.x, tid = threadIdx.x;

  if (idx < 144) {
    int pt = idx % 36, z = idx / 36;
    int b = z & 1, which = z >> 1;
    int pos0 = pt * 64;
    const float* src = (which ? ehs : hs) + (size_t)b * Cc * Pc;
    ushort* dst = (which ? ehsT : hsT) + (size_t)b * Pc * Cc;
    float* t = smem;               // [64][65] = 4160
    float* s1 = smem + 4160;       // [4][64]
    float* s2 = smem + 4416;
    float* lmean = smem + 4672;    // [64]
    float* lrstd = smem + 4736;    // [64]
    int lane = tid & 63, g = tid >> 6;
    if (which) {
      const float* base = src + pos0 + lane;
      float sum = 0.f, sq = 0.f;
      for (int c = g * 80; c < g * 80 + 80; ++c) {
        float x = base[(size_t)c * Pc];
        sum += x; sq += x * x;
      }
      s1[g * 64 + lane] = sum; s2[g * 64 + lane] = sq;
      __syncthreads();
      if (tid < 64) {
        float ts = s1[tid] + s1[64 + tid] + s1[128 + tid] + s1[192 + tid];
        float tq = s2[tid] + s2[64 + tid] + s2[128 + tid] + s2[192 + tid];
        float mean = ts / (float)Cc;
        float var = tq / (float)Cc - mean * mean;
        lmean[tid] = mean;
        lrstd[tid] = rsqrtf(var + LN_EPS);
      }
      __syncthreads();
    }
    // register-prefetched 5-tile loop
    float4 pv[4];
#pragma unroll
    for (int it = 0; it < 4; ++it) {
      int lin = it * 256 + tid, rr = lin >> 4, c4 = lin & 15;
      pv[it] = *(const float4*)(&src[(size_t)rr * Pc + pos0 + c4 * 4]);
    }
    for (int ct = 0; ct < 5; ++ct) {
      int r0 = ct * 64;
#pragma unroll
      for (int it = 0; it < 4; ++it) {
        int lin = it * 256 + tid, rr = lin >> 4, c4 = lin & 15;
        t[rr * 65 + c4 * 4 + 0] = pv[it].x;
        t[rr * 65 + c4 * 4 + 1] = pv[it].y;
        t[rr * 65 + c4 * 4 + 2] = pv[it].z;
        t[rr * 65 + c4 * 4 + 3] = pv[it].w;
      }
      __syncthreads();
      if (ct < 4) {
#pragma unroll
        for (int it = 0; it < 4; ++it) {
          int lin = it * 256 + tid, rr = lin >> 4, c4 = lin & 15;
          pv[it] =
              *(const float4*)(&src[(size_t)(r0 + 64 + rr) * Pc + pos0 + c4 * 4]);
        }
      }
#pragma unroll
      for (int it = 0; it < 2; ++it) {
        int lin = it * 256 + tid;
        int cc = lin >> 3, r8 = lin & 7;
        float m_ = which ? lmean[cc] : 0.f, rs_ = which ? lrstd[cc] : 1.f;
        ushort tmp[8];
#pragma unroll
        for (int j = 0; j < 8; ++j) {
          int ch = r8 * 8 + j;
          float x = t[ch * 65 + cc];
          float val = which ? (x - m_) * rs_ * gamma[r0 + ch] + beta[r0 + ch] : x;
          tmp[j] = f2bf(val);
        }
        *(uint4*)(&dst[(size_t)(pos0 + cc) * Cc + r0 + r8 * 8]) =
            *(const uint4*)tmp;
      }
      __syncthreads();
    }
  } else {
    int idx2 = idx - 144;
    if (idx2 < 40) {
      transpose_tile(Wv, WvT, Cc, INNERc, (idx2 / 8) * 64, (idx2 % 8) * 64,
                     tid, (float(*)[65])smem);
    } else if (idx2 < 80) {
      int i = idx2 - 40;
      transpose_tile(Wo, WoT, INNERc, Cc, (i / 5) * 64, (i % 5) * 64, tid,
                     (float(*)[65])smem);
    } else {
      int i = idx2 - 80;
      int c0 = (i % 5) * 64, h = (i / 5) % 8, zz = i / 40;
      const float* filt = zz ? dif : exf;
      const float* W = zz ? Wq : Wk;
      ushort* G = zz ? Gq : Gk;
      float (*ef)[66] = (float(*)[66])smem;
      float (*wk)[65] = (float(*)[65])(smem + 32 * 66);
      for (int l = tid; l < Fc * DHc; l += 256) {
        int f = l >> 6, d = l & 63;
        ef[f][d] = filt[(size_t)f * INNERc + h * 64 + d];
      }
      for (int l = tid; l < 64 * DHc; l += 256) {
        int cc = l >> 6, d = l & 63;
        wk[cc][d] = W[(size_t)(c0 + cc) * INNERc + h * 64 + d];
      }
      __syncthreads();
      int f = tid >> 3, cbase = tid & 7;
      float acc[8] = {};
#pragma unroll
      for (int d4 = 0; d4 < DHc; d4 += 4) {
        float4 a = *(const float4*)(&ef[f][d4]);
#pragma unroll
        for (int j = 0; j < 8; ++j) {
          float4 b = *(const float4*)(&wk[cbase + j * 8][d4]);
          acc[j] += a.x * b.x + a.y * b.y + a.z * b.z + a.w * b.w;
        }
      }
#pragma unroll
      for (int j = 0; j < 8; ++j)
        G[(size_t)(h * Fc + f) * Cc + c0 + cbase + j * 8] = f2bf(acc[j]);
    }
  }
}

// ---------------------------------------------------------------------------
// 2. Spatial attention, CHUNK_P=64 -> 576 blocks. Double-buffered staging
//    (2-phase pipeline): stage(t+1) issued BEFORE MFMA(t); one barrier/iter.
//    LDS = 2 x 20480 staging; phase-2 {Sq,Vs,P} overlays dead buffers.
// ---------------------------------------------------------------------------
__global__ __launch_bounds__(256) void spatial_kernel(
    const ushort* __restrict__ Gk, const ushort* __restrict__ ehsT,
    const ushort* __restrict__ WvT, const float* __restrict__ scale_p,
    float* __restrict__ svp, float* __restrict__ mj, float* __restrict__ lj) {
  int c = blockIdx.x, h = blockIdx.y, b = blockIdx.z;
  int tid = threadIdx.x, lane = tid & 63, wv = tid >> 6;
  int l15 = lane & 15, kq = lane >> 4;
  int pos0 = c * CHUNK_P;
  int bh = b * HEADSc + h;
  float s = scale_p[0];

  __shared__ alignas(16) char smem[40960];
  float* Sq = (float*)smem;              // [32][68] fp32
  ushort* Vs = (ushort*)(smem + 8704);   // [64][72]
  ushort* P = (ushort*)(smem + 17920);   // [32][72]

  const ushort* Av = WvT + (size_t)(h * 64) * Cc;
  const ushort* Ag = Gk + (size_t)(h * Fc) * Cc;
  const ushort* Bb = ehsT + ((size_t)b * Pc + pos0) * Cc;

  auto stage = [&](int buf, int k0) {
    ushort* As_ = (ushort*)(smem + buf * 20480);
    ushort* Bs_ = (ushort*)(smem + buf * 20480 + 12288);
#pragma unroll
    for (int it = 0; it < 3; ++it) {
      int lin = it * 256 + tid;       // 768: 96 rows x 8
      int row = lin >> 3, p = lin & 7;
      int lc = p ^ (row & 7);
      const ushort* sp = (row < 64)
                             ? (Av + (size_t)row * Cc + k0 + lc * 8)
                             : (Ag + (size_t)(row - 64) * Cc + k0 + lc * 8);
      gload16(sp, &As_[lin * 8]);
    }
#pragma unroll
    for (int it = 0; it < 2; ++it) {
      int lin = it * 256 + tid;       // 512: 64 rows x 8
      int row = lin >> 3, p = lin & 7;
      int lc = p ^ (row & 7);
      gload16(Bb + (size_t)row * Cc + k0 + lc * 8, &Bs_[lin * 8]);
    }
  };

  f32x4 acc[6] = {};
  stage(0, 0);
  __syncthreads();
  int cur = 0;
  for (int t = 0; t < 5; ++t) {
    if (t < 4) stage(cur ^ 1, (t + 1) * 64);
    const ushort* As_ = (const ushort*)(smem + cur * 20480);
    const ushort* Bs_ = (const ushort*)(smem + cur * 20480 + 12288);
#pragma unroll
    for (int ss = 0; ss < 2; ++ss) {
      bf16x8 af[6], bfr;
#pragma unroll
      for (int mt = 0; mt < 6; ++mt) {
        int m = mt * 16 + l15;
        int p = (ss * 4 + kq) ^ (m & 7);
        af[mt] = *(const bf16x8*)(&As_[m * 64 + p * 8]);
      }
      {
        int n = wv * 16 + l15;
        int p = (ss * 4 + kq) ^ (n & 7);
        bfr = *(const bf16x8*)(&Bs_[n * 64 + p * 8]);
      }
#pragma unroll
      for (int mt = 0; mt < 6; ++mt)
        acc[mt] = __builtin_amdgcn_mfma_f32_16x16x32_bf16(af[mt], bfr, acc[mt],
                                                          0, 0, 0);
    }
    __syncthreads();
    cur ^= 1;
  }
  // scatter: mt<4 -> Vs (bf16) [d][pos], mt 4..5 -> Sq (fp32) [f][pos]
#pragma unroll
  for (int mt = 0; mt < 6; ++mt) {
    int col = wv * 16 + l15;
#pragma unroll
    for (int r = 0; r < 4; ++r) {
      int row = mt * 16 + kq * 4 + r;
      if (mt < 4) Vs[row * 72 + col] = f2bf(acc[mt][r]);
      else Sq[(row - 64) * 68 + col] = acc[mt][r];
    }
  }
  __syncthreads();

  // per-row (f) local max + exp-sum over 64 cols; P = exp(s*S - m)
  {
    int row = tid >> 3, sub = tid & 7;
    float vals[8];
    float m_ = -1e30f;
#pragma unroll
    for (int i = 0; i < 8; ++i) {
      vals[i] = s * Sq[row * 68 + sub * 8 + i];
      m_ = fmaxf(m_, vals[i]);
    }
    m_ = fmaxf(m_, __shfl_xor(m_, 1));
    m_ = fmaxf(m_, __shfl_xor(m_, 2));
    m_ = fmaxf(m_, __shfl_xor(m_, 4));
    float l_ = 0.f;
#pragma unroll
    for (int i = 0; i < 8; i += 2) {
      float e0 = __expf(vals[i] - m_);
      float e1 = __expf(vals[i + 1] - m_);
      l_ += e0 + e1;
      uint pk = (uint)f2bf(e0) | ((uint)f2bf(e1) << 16);
      *(uint*)(&P[row * 72 + sub * 8 + i]) = pk;
    }
    l_ += __shfl_xor(l_, 1);
    l_ += __shfl_xor(l_, 2);
    l_ += __shfl_xor(l_, 4);
    if (sub == 0) {
      mj[((size_t)c * 16 + bh) * Fc + row] = m_;
      lj[((size_t)c * 16 + bh) * Fc + row] = l_;
    }
  }
  __syncthreads();

  // O = P(32x64) . V^T  (M=32, N=64, K=64)
  f32x4 acc2[2] = {};
#pragma unroll
  for (int ss = 0; ss < 2; ++ss) {
    bf16x8 af[2];
#pragma unroll
    for (int mt = 0; mt < 2; ++mt)
      af[mt] = *(const bf16x8*)(&P[(mt * 16 + l15) * 72 + ss * 32 + kq * 8]);
    bf16x8 bfr = *(const bf16x8*)(&Vs[(wv * 16 + l15) * 72 + ss * 32 + kq * 8]);
#pragma unroll
    for (int mt = 0; mt < 2; ++mt)
      acc2[mt] = __builtin_amdgcn_mfma_f32_16x16x32_bf16(af[mt], bfr, acc2[mt],
                                                         0, 0, 0);
  }
  float* op = svp + ((size_t)c * 16 + bh) * (Fc * DHc);
#pragma unroll
  for (int mt = 0; mt < 2; ++mt)
#pragma unroll
    for (int r = 0; r < 4; ++r)
      op[(mt * 16 + kq * 4 + r) * DHc + wv * 16 + l15] = acc2[mt][r];
}

// ---------------------------------------------------------------------------
// 3. Online-softmax reduce of 36 chunks -> svT[bh][d][f] bf16
// ---------------------------------------------------------------------------
__global__ __launch_bounds__(256) void sv_reduce_kernel(
    const float* __restrict__ svp, const float* __restrict__ mj,
    const float* __restrict__ lj, ushort* __restrict__ svT) {
  int idx = blockIdx.x * 256 + threadIdx.x;  // 32768
  int d = idx & 63, fr = idx >> 6;
  int bh = fr >> 5, f = fr & 31;
  float m = -1e30f;
#pragma unroll
  for (int c = 0; c < CHUNKS; ++c)
    m = fmaxf(m, mj[((size_t)c * 16 + bh) * Fc + f]);
  float osum = 0.f, lsum = 0.f;
#pragma unroll 4
  for (int c = 0; c < CHUNKS; ++c) {
    float w = __expf(mj[((size_t)c * 16 + bh) * Fc + f] - m);
    osum += w * svp[((size_t)c * 16 + bh) * (Fc * DHc) + f * DHc + d];
    lsum += w * lj[((size_t)c * 16 + bh) * Fc + f];
  }
  svT[((size_t)bh * DHc + d) * Fc + f] = f2bf(osum / lsum);
}

// ---------------------------------------------------------------------------
// 4. Channel attention, one head per block -> 576 blocks. Double-buffered
//    2-phase staging; phase-2 {SO,Pt,svs,red} overlays dead staging buffers.
// ---------------------------------------------------------------------------
__global__ __launch_bounds__(256) void channel_kernel(
    const ushort* __restrict__ Gq, const ushort* __restrict__ hsT,
    const ushort* __restrict__ svT, const float* __restrict__ scale_p,
    ushort* __restrict__ OAT) {
  int pb = blockIdx.x, h = blockIdx.y, b = blockIdx.z;
  int pos0 = pb * 64;
  int tid = threadIdx.x, lane = tid & 63, wv = tid >> 6;
  int l15 = lane & 15, kq = lane >> 4;
  float s = scale_p[0];

  __shared__ alignas(16) char smem[28672];
  float* SO = (float*)smem;               // [64][68]
  ushort* Pt = (ushort*)(smem + 17408);   // [64][40]
  ushort* svs = (ushort*)(smem + 22528);  // [64][40]
  float* red = (float*)(smem + 27648);    // [4][64]

  const ushort* Bb = hsT + ((size_t)b * Pc + pos0) * Cc;
  const ushort* Ab = Gq + (size_t)(h * Fc) * Cc;

  auto stage = [&](int buf, int k0) {
    ushort* Aq_ = (ushort*)(smem + buf * 12288);
    ushort* Bs_ = (ushort*)(smem + buf * 12288 + 4096);
    {
      int lin = tid, row = lin >> 3, p = lin & 7;
      int lc = p ^ (row & 7);
      gload16(Ab + (size_t)row * Cc + k0 + lc * 8, &Aq_[lin * 8]);
    }
#pragma unroll
    for (int it = 0; it < 2; ++it) {
      int lin = it * 256 + tid, row = lin >> 3, p = lin & 7;
      int lc = p ^ (row & 7);
      gload16(Bb + (size_t)row * Cc + k0 + lc * 8, &Bs_[lin * 8]);
    }
  };

  f32x4 acc[2] = {};
  stage(0, 0);
  __syncthreads();
  int cur = 0;
  for (int t = 0; t < 5; ++t) {
    if (t < 4) stage(cur ^ 1, (t + 1) * 64);
    const ushort* Aq_ = (const ushort*)(smem + cur * 12288);
    const ushort* Bs_ = (const ushort*)(smem + cur * 12288 + 4096);
#pragma unroll
    for (int ss = 0; ss < 2; ++ss) {
      int n = wv * 16 + l15;
      int pb_ = (ss * 4 + kq) ^ (n & 7);
      bf16x8 bfr = *(const bf16x8*)(&Bs_[n * 64 + pb_ * 8]);
#pragma unroll
      for (int mt = 0; mt < 2; ++mt) {
        int m = mt * 16 + l15;
        int pa = (ss * 4 + kq) ^ (m & 7);
        bf16x8 af = *(const bf16x8*)(&Aq_[m * 64 + pa * 8]);
        acc[mt] = __builtin_amdgcn_mfma_f32_16x16x32_bf16(af, bfr, acc[mt],
                                                          0, 0, 0);
      }
    }
    __syncthreads();
    cur ^= 1;
  }

  // scatter scores -> SO rows 0..31 (f), cols 0..63 (pos); load svs
#pragma unroll
  for (int mt = 0; mt < 2; ++mt)
#pragma unroll
    for (int r = 0; r < 4; ++r)
      SO[(mt * 16 + kq * 4 + r) * 68 + wv * 16 + l15] = acc[mt][r];
  {
    int rr = tid >> 2, p = tid & 3;
    *(uint4*)(&svs[rr * 40 + p * 8]) = *(const uint4*)(
        svT + ((size_t)(b * HEADSc + h) * DHc + rr) * Fc + p * 8);
  }
  __syncthreads();
  // softmax over f (32) per pos (64)
  {
    int pos = tid & 63, g = tid >> 6;
    float v8[8];
    float pm = -1e30f;
#pragma unroll
    for (int i = 0; i < 8; ++i) {
      v8[i] = s * SO[(g * 8 + i) * 68 + pos];
      pm = fmaxf(pm, v8[i]);
    }
    red[g * 64 + pos] = pm;
    __syncthreads();
    float m_ = fmaxf(fmaxf(red[pos], red[64 + pos]),
                     fmaxf(red[128 + pos], red[192 + pos]));
    __syncthreads();
    float ps = 0.f;
#pragma unroll
    for (int i = 0; i < 8; ++i) {
      v8[i] = __expf(v8[i] - m_);
      ps += v8[i];
    }
    red[g * 64 + pos] = ps;
    __syncthreads();
    float inv = 1.f / (red[pos] + red[64 + pos] + red[128 + pos] +
                       red[192 + pos]);
#pragma unroll
    for (int i = 0; i < 8; i += 2) {
      uint pk = (uint)f2bf(v8[i] * inv) | ((uint)f2bf(v8[i + 1] * inv) << 16);
      *(uint*)(&Pt[pos * 40 + g * 8 + i]) = pk;
    }
  }
  __syncthreads();
  // PV: out[pos 64][d 64] = Pt(64x32) . svs^T ; write into SO rows 0..63
  {
    bf16x8 b_ = *(const bf16x8*)(&svs[(wv * 16 + l15) * 40 + kq * 8]);
    f32x4 acc3[4];
#pragma unroll
    for (int mt = 0; mt < 4; ++mt) {
      bf16x8 a_ = *(const bf16x8*)(&Pt[(mt * 16 + l15) * 40 + kq * 8]);
      f32x4 z = {0.f, 0.f, 0.f, 0.f};
      acc3[mt] = __builtin_amdgcn_mfma_f32_16x16x32_bf16(a_, b_, z, 0, 0, 0);
    }
#pragma unroll
    for (int mt = 0; mt < 4; ++mt)
#pragma unroll
      for (int r = 0; r < 4; ++r)
        SO[(mt * 16 + kq * 4 + r) * 68 + wv * 16 + l15] = acc3[mt][r];
  }
  __syncthreads();
#pragma unroll
  for (int it = 0; it < 2; ++it) {
    int lin = it * 256 + tid;
    int p = lin >> 3, c8 = lin & 7;
    ushort tmp[8];
#pragma unroll
    for (int j = 0; j < 8; ++j) tmp[j] = f2bf(SO[p * 68 + c8 * 8 + j]);
    *(uint4*)(&OAT[((size_t)b * Pc + pos0 + p) * INNERc + h * 64 + c8 * 8]) =
        *(const uint4*)tmp;
  }
}

// ---------------------------------------------------------------------------
// 5. Final GEMM: out = WoT . OAT + bias + s*res. K=512, 64x64 tiles,
//    double-buffered 2-phase staging (8 K-iterations).
// ---------------------------------------------------------------------------
__global__ __launch_bounds__(256) void gemm_mfma_kernel(
    const ushort* __restrict__ A, const ushort* __restrict__ Bt,
    float* __restrict__ Out, int K, int Mdim,
    const float* __restrict__ bias, const float* __restrict__ res,
    const float* __restrict__ scale_p) {
  int b = blockIdx.z;
  int n0 = blockIdx.x * 64, m0 = blockIdx.y * 64;
  int tid = threadIdx.x, lane = tid & 63, wv = tid >> 6;
  int l15 = lane & 15, kq = lane >> 4;
  __shared__ alignas(16) char smem[32768];
  const ushort* Ab = A + (size_t)m0 * K;
  const ushort* Bb = Bt + ((size_t)b * Pc + n0) * K;

  auto stage = [&](int buf, int k0) {
    ushort* As_ = (ushort*)(smem + buf * 16384);
    ushort* Bs_ = (ushort*)(smem + buf * 16384 + 8192);
#pragma unroll
    for (int it = 0; it < 2; ++it) {
      int lin = it * 256 + tid, row = lin >> 3, p = lin & 7;
      int lc = p ^ (row & 7);
      gload16(Ab + (size_t)row * K + k0 + lc * 8, &As_[lin * 8]);
    }
#pragma unroll
    for (int it = 0; it < 2; ++it) {
      int lin = it * 256 + tid, row = lin >> 3, p = lin & 7;
      int lc = p ^ (row & 7);
      gload16(Bb + (size_t)row * K + k0 + lc * 8, &Bs_[lin * 8]);
    }
  };

  f32x4 acc[4] = {};
  stage(0, 0);
  __syncthreads();
  int cur = 0;
  const int NT = K >> 6;  // 8
  for (int t = 0; t < NT; ++t) {
    if (t < NT - 1) stage(cur ^ 1, (t + 1) * 64);
    const ushort* As_ = (const ushort*)(smem + cur * 16384);
    const ushort* Bs_ = (const ushort*)(smem + cur * 16384 + 8192);
#pragma unroll
    for (int ss = 0; ss < 2; ++ss) {
      bf16x8 af[4], bfr;
#pragma unroll
      for (int mt = 0; mt < 4; ++mt) {
        int m = mt * 16 + l15;
        int p = (ss * 4 + kq) ^ (m & 7);
        af[mt] = *(const bf16x8*)(&As_[m * 64 + p * 8]);
      }
      {
        int n = wv * 16 + l15;
        int p = (ss * 4 + kq) ^ (n & 7);
        bfr = *(const bf16x8*)(&Bs_[n * 64 + p * 8]);
      }
#pragma unroll
      for (int mt = 0; mt < 4; ++mt)
        acc[mt] = __builtin_amdgcn_mfma_f32_16x16x32_bf16(af[mt], bfr, acc[mt],
                                                          0, 0, 0);
    }
    __syncthreads();
    cur ^= 1;
  }
  float s = scale_p[0];
  float* Ob = Out + ((size_t)b * Mdim + m0) * Pc + n0;
  const float* rb = res + ((size_t)b * Mdim + m0) * Pc + n0;
  int ncol = wv * 16 + l15;
#pragma unroll
  for (int mt = 0; mt < 4; ++mt)
#pragma unroll
    for (int r = 0; r < 4; ++r) {
      int m = mt * 16 + kq * 4 + r;
      Ob[(size_t)m * Pc + ncol] =
          acc[mt][r] + bias[m0 + m] + s * rb[(size_t)m * Pc + ncol];
    }
}

// ---------------------------------------------------------------------------
extern "C" void kernel_launch(void* const* d_in, const int* in_sizes, int n_in,
                              void* d_out, int out_size, void* d_ws, size_t ws_size,
                              hipStream_t stream) {
  const float* hs    = (const float*)d_in[0];
  const float* ehs   = (const float*)d_in[1];
  const float* Wq    = (const float*)d_in[2];
  const float* Wk    = (const float*)d_in[3];
  const float* Wv    = (const float*)d_in[4];
  const float* Wo    = (const float*)d_in[5];
  const float* bo    = (const float*)d_in[6];
  const float* gamma = (const float*)d_in[7];
  const float* beta  = (const float*)d_in[8];
  const float* exf   = (const float*)d_in[9];
  const float* dif   = (const float*)d_in[10];
  const float* scale = (const float*)d_in[11];
  float* out = (float*)d_out;

  float* ws = (float*)d_ws;
  float* svp = ws;                         // 36*16*2048 = 1,179,648 f
  float* mj  = svp + 1179648;              //    18,432 f
  float* lj  = mj + 18432;                 //    18,432 f
  ushort* hsT  = (ushort*)(lj + 18432);    // 1,474,560 us
  ushort* ehsT = hsT + 1474560;            // 1,474,560 us
  ushort* WvT  = ehsT + 1474560;           //   163,840 us
  ushort* WoT  = WvT + 163840;             //   163,840 us
  ushort* Gk   = WoT + 163840;             //    81,920 us
  ushort* Gq   = Gk + 81920;               //    81,920 us
  ushort* svT  = Gq + 81920;               //    32,768 us
  ushort* OAT  = svT + 32768;              // 2,359,296 us

  prep_all_kernel<<<dim3(304), dim3(256), 0, stream>>>(
      hs, ehs, gamma, beta, Wv, Wo, exf, Wk, dif, Wq,
      hsT, ehsT, WvT, WoT, Gk, Gq);
  spatial_kernel<<<dim3(CHUNKS, HEADSc, Bc), dim3(256), 0, stream>>>(
      Gk, ehsT, WvT, scale, svp, mj, lj);
  sv_reduce_kernel<<<dim3(128), dim3(256), 0, stream>>>(svp, mj, lj, svT);
  channel_kernel<<<dim3(Pc / 64, HEADSc, Bc), dim3(256), 0, stream>>>(
      Gq, hsT, svT, scale, OAT);
  gemm_mfma_kernel<<<dim3(Pc / 64, Cc / 64, Bc), dim3(256), 0, stream>>>(
      WoT, OAT, out, INNERc, Cc, bo, hs, scale);
}